// Round 1
// baseline (1140.496 us; speedup 1.0000x reference)
//
#include <hip/hip_runtime.h>
#include <hip/hip_bf16.h>

#define EPS 1e-5f

// ---------------- init: deg=1 (self-loop), zero stats ----------------
__global__ void k_init(float* __restrict__ deg, float* __restrict__ stats, int N) {
    int t = blockIdx.x * blockDim.x + threadIdx.x;
    if (t < N) deg[t] = 1.0f;
    if (t < 512) stats[t] = 0.0f;
}

// ---------------- column stats of x [N x 128] ----------------
__global__ void k_colstats_x(const float* __restrict__ x, float* __restrict__ xsum,
                             float* __restrict__ xsq, int N) {
    __shared__ float ls[256], lq[256];
    int tx = threadIdx.x;
    int col = tx & 127, half = tx >> 7;
    float s = 0.f, q = 0.f;
    for (int r = blockIdx.x * 2 + half; r < N; r += gridDim.x * 2) {
        float v = x[(long long)r * 128 + col];
        s += v; q += v * v;
    }
    ls[tx] = s; lq[tx] = q;
    __syncthreads();
    if (half == 0) {
        s = ls[tx] + ls[tx + 128];
        q = lq[tx] + lq[tx + 128];
        atomicAdd(&xsum[col], s);
        atomicAdd(&xsq[col], q);
    }
}

// ---------------- fold BN_in into Wp -> Wfold, bfold ----------------
__global__ void k_fold(const float* __restrict__ stats, const float* __restrict__ g,
                       const float* __restrict__ b, const float* __restrict__ Wp,
                       const float* __restrict__ bp, float* __restrict__ Wfold,
                       float* __restrict__ bfold, float invN) {
    __shared__ float sc[128], sh[128];
    int tx = threadIdx.x;
    if (tx < 128) {
        float mu = stats[tx] * invN;
        float var = stats[128 + tx] * invN - mu * mu;
        float s = g[tx] * rsqrtf(var + EPS);
        sc[tx] = s;
        sh[tx] = b[tx] - mu * s;
    }
    __syncthreads();
    for (int i = tx; i < 128 * 64; i += 256) {
        int c = i >> 6;
        Wfold[i] = Wp[i] * sc[c];
    }
    if (tx < 64) {
        float acc = bp[tx];
        for (int c = 0; c < 128; c++) acc += sh[c] * Wp[c * 64 + tx];
        bfold[tx] = acc;
    }
}

// ---------------- gemm1: relu(x @ Wfold + bfold) -> A [N x 64] ----------------
__global__ __launch_bounds__(256) void k_gemm1(const float* __restrict__ x,
                                               const float* __restrict__ Wf,
                                               const float* __restrict__ bf,
                                               float* __restrict__ A, int N) {
    int r = blockIdx.x * blockDim.x + threadIdx.x;
    if (r >= N) return;
    float acc[64];
#pragma unroll
    for (int j = 0; j < 64; j++) acc[j] = 0.f;
    const float4* x4 = (const float4*)(x + (long long)r * 128);
    for (int c4 = 0; c4 < 32; c4++) {
        float4 xv = x4[c4];
#pragma unroll
        for (int q = 0; q < 4; q++) {
            float xs = (q == 0) ? xv.x : (q == 1) ? xv.y : (q == 2) ? xv.z : xv.w;
            const float* wrow = Wf + (c4 * 4 + q) * 64;
#pragma unroll
            for (int j = 0; j < 64; j++) acc[j] += xs * wrow[j];
        }
    }
    float4* out4 = (float4*)(A + (long long)r * 64);
#pragma unroll
    for (int i = 0; i < 16; i++) {
        float4 v;
        v.x = fmaxf(acc[4 * i + 0] + bf[4 * i + 0], 0.f);
        v.y = fmaxf(acc[4 * i + 1] + bf[4 * i + 1], 0.f);
        v.z = fmaxf(acc[4 * i + 2] + bf[4 * i + 2], 0.f);
        v.w = fmaxf(acc[4 * i + 3] + bf[4 * i + 3], 0.f);
        out4[i] = v;
    }
}

// ---------------- degree accumulation ----------------
__global__ void k_deg(const int* __restrict__ dst, float* __restrict__ deg, int E) {
    int t = blockIdx.x * blockDim.x + threadIdx.x;
    if (t < E) atomicAdd(&deg[dst[t]], 1.0f);
}

__global__ void k_dinv(float* __restrict__ deg, int N) {
    int t = blockIdx.x * blockDim.x + threadIdx.x;
    if (t < N) deg[t] = rsqrtf(deg[t]);  // deg >= 1 always (self-loop)
}

// ------- gemm_scale: hs = (optional BN+relu(In)) @ W * dinv[row]; C init = hs -------
template <bool BNRELU>
__global__ __launch_bounds__(256) void k_gemm_scale(
    const float* __restrict__ In, const float* __restrict__ W,
    const float* __restrict__ dinv, const float* __restrict__ sc,
    const float* __restrict__ sh, float* __restrict__ Bout,
    float* __restrict__ Cinit, int N) {
    int r = blockIdx.x * blockDim.x + threadIdx.x;
    if (r >= N) return;
    float acc[64];
#pragma unroll
    for (int j = 0; j < 64; j++) acc[j] = 0.f;
    const float4* in4 = (const float4*)(In + (long long)r * 64);
    for (int c4 = 0; c4 < 16; c4++) {
        float4 xv = in4[c4];
        if (BNRELU) {
            int cb = c4 * 4;
            xv.x = fmaxf(xv.x * sc[cb + 0] + sh[cb + 0], 0.f);
            xv.y = fmaxf(xv.y * sc[cb + 1] + sh[cb + 1], 0.f);
            xv.z = fmaxf(xv.z * sc[cb + 2] + sh[cb + 2], 0.f);
            xv.w = fmaxf(xv.w * sc[cb + 3] + sh[cb + 3], 0.f);
        }
#pragma unroll
        for (int q = 0; q < 4; q++) {
            float xs = (q == 0) ? xv.x : (q == 1) ? xv.y : (q == 2) ? xv.z : xv.w;
            const float* wrow = W + (c4 * 4 + q) * 64;
#pragma unroll
            for (int j = 0; j < 64; j++) acc[j] += xs * wrow[j];
        }
    }
    float dv = dinv[r];
    float4* b4 = (float4*)(Bout + (long long)r * 64);
    float4* c4p = (float4*)(Cinit + (long long)r * 64);
#pragma unroll
    for (int i = 0; i < 16; i++) {
        float4 v;
        v.x = acc[4 * i + 0] * dv;
        v.y = acc[4 * i + 1] * dv;
        v.z = acc[4 * i + 2] * dv;
        v.w = acc[4 * i + 3] * dv;
        b4[i] = v;
        c4p[i] = v;
    }
}

// ---------------- scatter: one wave per edge, lane = feature ----------------
__global__ __launch_bounds__(256) void k_scatter(const int* __restrict__ src,
                                                 const int* __restrict__ dst,
                                                 const float* __restrict__ B,
                                                 float* __restrict__ C, int E) {
    int lane = threadIdx.x & 63;
    int w = (blockIdx.x * blockDim.x + threadIdx.x) >> 6;
    int stride = (gridDim.x * blockDim.x) >> 6;
    for (int e = w; e < E; e += stride) {
        int s = src[e];
        int d = dst[e];
        float v = B[s * 64 + lane];
        atomicAdd(&C[d * 64 + lane], v);
    }
}

// ------- finish: h = dinv[r]*C + b -> Out; accumulate column stats -------
__global__ void k_finish_stats(const float* __restrict__ C, const float* __restrict__ dinv,
                               const float* __restrict__ bias, float* __restrict__ Out,
                               float* __restrict__ ssum, float* __restrict__ ssq, int N) {
    __shared__ float ls[256], lq[256];
    int tx = threadIdx.x;
    int j = tx & 63, rq = tx >> 6;
    float bj = bias[j];
    float s = 0.f, q = 0.f;
    for (int r = blockIdx.x * 4 + rq; r < N; r += gridDim.x * 4) {
        float v = dinv[r] * C[(long long)r * 64 + j] + bj;
        Out[(long long)r * 64 + j] = v;
        s += v; q += v * v;
    }
    ls[tx] = s; lq[tx] = q;
    __syncthreads();
    if (rq == 0) {
        s = ls[tx] + ls[tx + 64] + ls[tx + 128] + ls[tx + 192];
        q = lq[tx] + lq[tx + 64] + lq[tx + 128] + lq[tx + 192];
        atomicAdd(&ssum[j], s);
        atomicAdd(&ssq[j], q);
    }
}

// ---------------- compute BN scale/shift from stats ----------------
__global__ void k_ss(const float* __restrict__ ssum, const float* __restrict__ ssq,
                     const float* __restrict__ g, const float* __restrict__ b,
                     float* __restrict__ sc, float* __restrict__ sh, float invN) {
    int t = threadIdx.x;
    if (t < 64) {
        float mu = ssum[t] * invN;
        float var = ssq[t] * invN - mu * mu;
        float s = g[t] * rsqrtf(var + EPS);
        sc[t] = s;
        sh[t] = b[t] - mu * s;
    }
}

// ---------------- final elementwise BN apply ----------------
__global__ void k_final(const float* __restrict__ In, const float* __restrict__ sc,
                        const float* __restrict__ sh, float* __restrict__ out, int total4) {
    int t = blockIdx.x * blockDim.x + threadIdx.x;
    if (t < total4) {
        float4 v = ((const float4*)In)[t];
        int j = (t * 4) & 63;
        v.x = v.x * sc[j + 0] + sh[j + 0];
        v.y = v.y * sc[j + 1] + sh[j + 1];
        v.z = v.z * sc[j + 2] + sh[j + 2];
        v.w = v.w * sc[j + 3] + sh[j + 3];
        ((float4*)out)[t] = v;
    }
}

extern "C" void kernel_launch(void* const* d_in, const int* in_sizes, int n_in,
                              void* d_out, int out_size, void* d_ws, size_t ws_size,
                              hipStream_t stream) {
    const float* x       = (const float*)d_in[0];
    const int*   ei      = (const int*)d_in[1];
    const float* bn_in_g = (const float*)d_in[2];
    const float* bn_in_b = (const float*)d_in[3];
    const float* Wp      = (const float*)d_in[4];
    const float* bp      = (const float*)d_in[5];
    const float* W1      = (const float*)d_in[6];
    const float* b1      = (const float*)d_in[7];
    const float* bn1_g   = (const float*)d_in[8];
    const float* bn1_b   = (const float*)d_in[9];
    const float* W2      = (const float*)d_in[10];
    const float* b2      = (const float*)d_in[11];
    const float* bn2_g   = (const float*)d_in[12];
    const float* bn2_b   = (const float*)d_in[13];

    int N = in_sizes[0] / 128;
    int E = in_sizes[1] / 2;
    const int* src = ei;
    const int* dst = ei + E;

    float* ws = (float*)d_ws;
    long long off = ((long long)N + 127) & ~127LL;
    float* deg   = ws;               // N (becomes dinv)
    float* stats = ws + off;         // 512
    float* sc1   = stats + 512;      // 64
    float* sh1   = sc1 + 64;
    float* sc2   = sh1 + 64;
    float* sh2   = sc2 + 64;
    float* Wfold = sh2 + 64;         // 8192
    float* bfold = Wfold + 8192;     // 64
    float* A     = bfold + 64;       // N*64
    float* Bbuf  = A + (long long)N * 64;  // N*64
    float* C     = (float*)d_out;    // N*64 accumulator, reused as final out

    int nb = (N + 255) / 256;
    float invN = 1.0f / (float)N;

    k_init<<<nb, 256, 0, stream>>>(deg, stats, N);
    k_colstats_x<<<1024, 256, 0, stream>>>(x, stats, stats + 128, N);
    k_fold<<<1, 256, 0, stream>>>(stats, bn_in_g, bn_in_b, Wp, bp, Wfold, bfold, invN);
    k_gemm1<<<nb, 256, 0, stream>>>(x, Wfold, bfold, A, N);
    k_deg<<<(E + 255) / 256, 256, 0, stream>>>(dst, deg, E);
    k_dinv<<<nb, 256, 0, stream>>>(deg, N);

    // conv1
    k_gemm_scale<false><<<nb, 256, 0, stream>>>(A, W1, deg, nullptr, nullptr, Bbuf, C, N);
    k_scatter<<<16384, 256, 0, stream>>>(src, dst, Bbuf, C, E);
    k_finish_stats<<<1024, 256, 0, stream>>>(C, deg, b1, A, stats + 256, stats + 320, N);
    k_ss<<<1, 64, 0, stream>>>(stats + 256, stats + 320, bn1_g, bn1_b, sc1, sh1, invN);

    // conv2
    k_gemm_scale<true><<<nb, 256, 0, stream>>>(A, W2, deg, sc1, sh1, Bbuf, C, N);
    k_scatter<<<16384, 256, 0, stream>>>(src, dst, Bbuf, C, E);
    k_finish_stats<<<1024, 256, 0, stream>>>(C, deg, b2, A, stats + 384, stats + 448, N);
    k_ss<<<1, 64, 0, stream>>>(stats + 384, stats + 448, bn2_g, bn2_b, sc2, sh2, invN);

    k_final<<<(N * 16 + 255) / 256, 256, 0, stream>>>(A, sc2, sh2, C, N * 16);
}

// Round 2
// 999.171 us; speedup vs baseline: 1.1414x; 1.1414x over previous
//
#include <hip/hip_runtime.h>
#include <hip/hip_bf16.h>

#define EPS 1e-5f

// ---------------- init: zero cnt[N] and stats[512] ----------------
__global__ void k_init(int* __restrict__ cnt, float* __restrict__ stats, int N) {
    int t = blockIdx.x * blockDim.x + threadIdx.x;
    if (t < N) cnt[t] = 0;
    if (t < 512) stats[t] = 0.0f;
}

// ---------------- histogram of dst ----------------
__global__ void k_hist(const int* __restrict__ dst, int* __restrict__ cnt, int E) {
    int t = blockIdx.x * blockDim.x + threadIdx.x;
    if (t < E) atomicAdd(&cnt[dst[t]], 1);
}

// ---------------- per-1024-block sums ----------------
__global__ void k_bsum(const int* __restrict__ cnt, int* __restrict__ bsum, int N) {
    __shared__ int ls[256];
    int tx = threadIdx.x;
    int i0 = blockIdx.x * 1024 + tx * 4;
    int s = 0;
#pragma unroll
    for (int j = 0; j < 4; j++)
        if (i0 + j < N) s += cnt[i0 + j];
    ls[tx] = s;
    __syncthreads();
    for (int st = 128; st > 0; st >>= 1) {
        if (tx < st) ls[tx] += ls[tx + st];
        __syncthreads();
    }
    if (tx == 0) bsum[blockIdx.x] = ls[0];
}

// ---------------- single-block exclusive scan of block sums (nb<=128) ----------------
__global__ void k_bscan(const int* __restrict__ bsum, int* __restrict__ boff, int nb) {
    int tx = threadIdx.x;  // 128 threads
    int v = (tx < nb) ? bsum[tx] : 0;
    int orig = v;
    int lane = tx & 63, wid = tx >> 6;
#pragma unroll
    for (int off = 1; off < 64; off <<= 1) {
        int u = __shfl_up(v, off);
        if (lane >= off) v += u;
    }
    __shared__ int w0;
    if (tx == 63) w0 = v;
    __syncthreads();
    if (wid == 1) v += w0;
    if (tx < nb) boff[tx] = v - orig;
}

// ------- per-block scan: rowptr, cursor, dinv = rsqrt(1+deg) -------
__global__ __launch_bounds__(256) void k_scan(const int* __restrict__ cnt,
                                              const int* __restrict__ boff,
                                              int* __restrict__ rowptr,
                                              int* __restrict__ cursor,
                                              float* __restrict__ dinv, int N, int E) {
    int tx = threadIdx.x;
    int i0 = blockIdx.x * 1024 + tx * 4;
    int c[4];
#pragma unroll
    for (int j = 0; j < 4; j++) c[j] = (i0 + j < N) ? cnt[i0 + j] : 0;
    int tot = c[0] + c[1] + c[2] + c[3];
    int lane = tx & 63, wid = tx >> 6;
    int v = tot;
#pragma unroll
    for (int off = 1; off < 64; off <<= 1) {
        int u = __shfl_up(v, off);
        if (lane >= off) v += u;
    }
    __shared__ int wsum[4];
    if (lane == 63) wsum[wid] = v;
    __syncthreads();
    int wbase = 0;
    for (int w = 0; w < wid; w++) wbase += wsum[w];
    int excl = boff[blockIdx.x] + wbase + (v - tot);
#pragma unroll
    for (int j = 0; j < 4; j++) {
        int i = i0 + j;
        if (i < N) {
            rowptr[i] = excl;
            cursor[i] = excl;
            dinv[i] = rsqrtf(1.0f + (float)c[j]);
            excl += c[j];
        }
    }
    if (blockIdx.x == 0 && tx == 0) rowptr[N] = E;
}

// ---------------- fill CSR buckets: eidx[slot] = src ----------------
__global__ void k_bucket(const int* __restrict__ src, const int* __restrict__ dst,
                         int* __restrict__ cursor, int* __restrict__ eidx, int E) {
    int t = blockIdx.x * blockDim.x + threadIdx.x;
    if (t < E) {
        int p = atomicAdd(&cursor[dst[t]], 1);
        eidx[p] = src[t];
    }
}

// ---------------- column stats of x [N x 128] ----------------
__global__ void k_colstats_x(const float* __restrict__ x, float* __restrict__ xsum,
                             float* __restrict__ xsq, int N) {
    __shared__ float ls[256], lq[256];
    int tx = threadIdx.x;
    int col = tx & 127, half = tx >> 7;
    float s = 0.f, q = 0.f;
    for (int r = blockIdx.x * 2 + half; r < N; r += gridDim.x * 2) {
        float v = x[(long long)r * 128 + col];
        s += v; q += v * v;
    }
    ls[tx] = s; lq[tx] = q;
    __syncthreads();
    if (half == 0) {
        s = ls[tx] + ls[tx + 128];
        q = lq[tx] + lq[tx + 128];
        atomicAdd(&xsum[col], s);
        atomicAdd(&xsq[col], q);
    }
}

// ---------------- fold BN_in into Wp -> Wfold, bfold ----------------
__global__ void k_fold(const float* __restrict__ stats, const float* __restrict__ g,
                       const float* __restrict__ b, const float* __restrict__ Wp,
                       const float* __restrict__ bp, float* __restrict__ Wfold,
                       float* __restrict__ bfold, float invN) {
    __shared__ float sc[128], sh[128];
    int tx = threadIdx.x;
    if (tx < 128) {
        float mu = stats[tx] * invN;
        float var = stats[128 + tx] * invN - mu * mu;
        float s = g[tx] * rsqrtf(var + EPS);
        sc[tx] = s;
        sh[tx] = b[tx] - mu * s;
    }
    __syncthreads();
    for (int i = tx; i < 128 * 64; i += 256) {
        int c = i >> 6;
        Wfold[i] = Wp[i] * sc[c];
    }
    if (tx < 64) {
        float acc = bp[tx];
        for (int c = 0; c < 128; c++) acc += sh[c] * Wp[c * 64 + tx];
        bfold[tx] = acc;
    }
}

// ---------------- gemm1: relu(x @ Wfold + bfold) -> H [N x 64] ----------------
__global__ __launch_bounds__(256) void k_gemm1(const float* __restrict__ x,
                                               const float* __restrict__ Wf,
                                               const float* __restrict__ bf,
                                               float* __restrict__ H, int N) {
    int r = blockIdx.x * blockDim.x + threadIdx.x;
    if (r >= N) return;
    float acc[64];
#pragma unroll
    for (int j = 0; j < 64; j++) acc[j] = 0.f;
    const float4* x4 = (const float4*)(x + (long long)r * 128);
    for (int c4 = 0; c4 < 32; c4++) {
        float4 xv = x4[c4];
#pragma unroll
        for (int q = 0; q < 4; q++) {
            float xs = (q == 0) ? xv.x : (q == 1) ? xv.y : (q == 2) ? xv.z : xv.w;
            const float* wrow = Wf + (c4 * 4 + q) * 64;
#pragma unroll
            for (int j = 0; j < 64; j++) acc[j] += xs * wrow[j];
        }
    }
    float4* out4 = (float4*)(H + (long long)r * 64);
#pragma unroll
    for (int i = 0; i < 16; i++) {
        float4 v;
        v.x = fmaxf(acc[4 * i + 0] + bf[4 * i + 0], 0.f);
        v.y = fmaxf(acc[4 * i + 1] + bf[4 * i + 1], 0.f);
        v.z = fmaxf(acc[4 * i + 2] + bf[4 * i + 2], 0.f);
        v.w = fmaxf(acc[4 * i + 3] + bf[4 * i + 3], 0.f);
        out4[i] = v;
    }
}

// ------- gemm_scale: hs = (optional BN+relu(In)) @ W * dinv[row] -> Bout -------
template <bool BNRELU>
__global__ __launch_bounds__(256) void k_gemm_scale(
    const float* __restrict__ In, const float* __restrict__ W,
    const float* __restrict__ dinv, const float* __restrict__ sc,
    const float* __restrict__ sh, float* __restrict__ Bout, int N) {
    int r = blockIdx.x * blockDim.x + threadIdx.x;
    if (r >= N) return;
    float acc[64];
#pragma unroll
    for (int j = 0; j < 64; j++) acc[j] = 0.f;
    const float4* in4 = (const float4*)(In + (long long)r * 64);
    for (int c4 = 0; c4 < 16; c4++) {
        float4 xv = in4[c4];
        if (BNRELU) {
            int cb = c4 * 4;
            xv.x = fmaxf(xv.x * sc[cb + 0] + sh[cb + 0], 0.f);
            xv.y = fmaxf(xv.y * sc[cb + 1] + sh[cb + 1], 0.f);
            xv.z = fmaxf(xv.z * sc[cb + 2] + sh[cb + 2], 0.f);
            xv.w = fmaxf(xv.w * sc[cb + 3] + sh[cb + 3], 0.f);
        }
#pragma unroll
        for (int q = 0; q < 4; q++) {
            float xs = (q == 0) ? xv.x : (q == 1) ? xv.y : (q == 2) ? xv.z : xv.w;
            const float* wrow = W + (c4 * 4 + q) * 64;
#pragma unroll
            for (int j = 0; j < 64; j++) acc[j] += xs * wrow[j];
        }
    }
    float dv = dinv[r];
    float4* b4 = (float4*)(Bout + (long long)r * 64);
#pragma unroll
    for (int i = 0; i < 16; i++) {
        float4 v;
        v.x = acc[4 * i + 0] * dv;
        v.y = acc[4 * i + 1] * dv;
        v.z = acc[4 * i + 2] * dv;
        v.w = acc[4 * i + 3] * dv;
        b4[i] = v;
    }
}

// ------- gather+finish: out[d] = dinv[d]*(hs[d] + sum_nbr hs[s]) + b; stats -------
// 16 lanes per node (float4 each = 64 feats), 16 nodes per 256-block.
__global__ __launch_bounds__(256) void k_gather_finish(
    const float* __restrict__ B, const int* __restrict__ rowptr,
    const int* __restrict__ eidx, const float* __restrict__ dinv,
    const float* __restrict__ bias, float* __restrict__ Out,
    float* __restrict__ ssum, float* __restrict__ ssq, int N) {
    int tx = threadIdx.x;
    int g = tx >> 4;   // node slot in block
    int l = tx & 15;   // feature quad
    float4 bq = ((const float4*)bias)[l];
    float s0 = 0, s1 = 0, s2 = 0, s3 = 0, q0 = 0, q1 = 0, q2 = 0, q3 = 0;
    for (int d = blockIdx.x * 16 + g; d < N; d += gridDim.x * 16) {
        int beg = rowptr[d], end = rowptr[d + 1];
        float4 acc = ((const float4*)(B + (long long)d * 64))[l];  // self term
        int k = beg;
        for (; k + 1 < end; k += 2) {
            int sA = eidx[k], sB = eidx[k + 1];
            float4 vA = ((const float4*)(B + (long long)sA * 64))[l];
            float4 vB = ((const float4*)(B + (long long)sB * 64))[l];
            acc.x += vA.x + vB.x; acc.y += vA.y + vB.y;
            acc.z += vA.z + vB.z; acc.w += vA.w + vB.w;
        }
        if (k < end) {
            int sA = eidx[k];
            float4 vA = ((const float4*)(B + (long long)sA * 64))[l];
            acc.x += vA.x; acc.y += vA.y; acc.z += vA.z; acc.w += vA.w;
        }
        float dv = dinv[d];
        acc.x = acc.x * dv + bq.x;
        acc.y = acc.y * dv + bq.y;
        acc.z = acc.z * dv + bq.z;
        acc.w = acc.w * dv + bq.w;
        ((float4*)(Out + (long long)d * 64))[l] = acc;
        s0 += acc.x; q0 += acc.x * acc.x;
        s1 += acc.y; q1 += acc.y * acc.y;
        s2 += acc.z; q2 += acc.z * acc.z;
        s3 += acc.w; q3 += acc.w * acc.w;
    }
    __shared__ float ls[256][4], lq[256][4];
    ls[tx][0] = s0; ls[tx][1] = s1; ls[tx][2] = s2; ls[tx][3] = s3;
    lq[tx][0] = q0; lq[tx][1] = q1; lq[tx][2] = q2; lq[tx][3] = q3;
    __syncthreads();
    if (tx < 16) {
        float S[4] = {0, 0, 0, 0}, Q[4] = {0, 0, 0, 0};
        for (int i = tx; i < 256; i += 16) {
#pragma unroll
            for (int q = 0; q < 4; q++) { S[q] += ls[i][q]; Q[q] += lq[i][q]; }
        }
#pragma unroll
        for (int q = 0; q < 4; q++) {
            atomicAdd(&ssum[tx * 4 + q], S[q]);
            atomicAdd(&ssq[tx * 4 + q], Q[q]);
        }
    }
}

// ---------------- compute BN scale/shift from stats ----------------
__global__ void k_ss(const float* __restrict__ ssum, const float* __restrict__ ssq,
                     const float* __restrict__ g, const float* __restrict__ b,
                     float* __restrict__ sc, float* __restrict__ sh, float invN) {
    int t = threadIdx.x;
    if (t < 64) {
        float mu = ssum[t] * invN;
        float var = ssq[t] * invN - mu * mu;
        float s = g[t] * rsqrtf(var + EPS);
        sc[t] = s;
        sh[t] = b[t] - mu * s;
    }
}

// ---------------- final elementwise BN apply (in-place safe) ----------------
__global__ void k_final(const float* __restrict__ In, const float* __restrict__ sc,
                        const float* __restrict__ sh, float* __restrict__ out, int total4) {
    int t = blockIdx.x * blockDim.x + threadIdx.x;
    if (t < total4) {
        float4 v = ((const float4*)In)[t];
        int j = (t * 4) & 63;
        v.x = v.x * sc[j + 0] + sh[j + 0];
        v.y = v.y * sc[j + 1] + sh[j + 1];
        v.z = v.z * sc[j + 2] + sh[j + 2];
        v.w = v.w * sc[j + 3] + sh[j + 3];
        ((float4*)out)[t] = v;
    }
}

extern "C" void kernel_launch(void* const* d_in, const int* in_sizes, int n_in,
                              void* d_out, int out_size, void* d_ws, size_t ws_size,
                              hipStream_t stream) {
    const float* x       = (const float*)d_in[0];
    const int*   ei      = (const int*)d_in[1];
    const float* bn_in_g = (const float*)d_in[2];
    const float* bn_in_b = (const float*)d_in[3];
    const float* Wp      = (const float*)d_in[4];
    const float* bp      = (const float*)d_in[5];
    const float* W1      = (const float*)d_in[6];
    const float* b1      = (const float*)d_in[7];
    const float* bn1_g   = (const float*)d_in[8];
    const float* bn1_b   = (const float*)d_in[9];
    const float* W2      = (const float*)d_in[10];
    const float* b2      = (const float*)d_in[11];
    const float* bn2_g   = (const float*)d_in[12];
    const float* bn2_b   = (const float*)d_in[13];

    int N = in_sizes[0] / 128;
    int E = in_sizes[1] / 2;
    const int* src = ei;
    const int* dst = ei + E;

    long long Npad = ((long long)N + 128) & ~127LL;  // >= N+1, 128-aligned
    int*   cnt    = (int*)d_ws;
    int*   rowptr = cnt + Npad;
    int*   cursor = rowptr + Npad;
    float* dinv   = (float*)(cursor + Npad);
    float* stats  = dinv + Npad;          // 512
    float* sc1    = stats + 512;          // 64
    float* sh1    = sc1 + 64;
    float* sc2    = sh1 + 64;
    float* sh2    = sc2 + 64;
    float* Wfold  = sh2 + 64;             // 8192
    float* bfold  = Wfold + 8192;         // 64
    int*   bsum   = (int*)(bfold + 64);   // 128
    int*   boff   = bsum + 128;           // 128
    int*   eidx   = boff + 128;           // E
    float* Bbuf   = (float*)(eidx + ((E + 127) & ~127)); // N*64
    float* H      = (float*)d_out;        // N*64 intermediate + final out

    int nb  = (N + 255) / 256;
    int nb2 = (N + 1023) / 1024;
    int eb  = (E + 255) / 256;
    float invN = 1.0f / (float)N;

    // CSR build
    k_init<<<nb, 256, 0, stream>>>(cnt, stats, N);
    k_hist<<<eb, 256, 0, stream>>>(dst, cnt, E);
    k_bsum<<<nb2, 256, 0, stream>>>(cnt, bsum, N);
    k_bscan<<<1, 128, 0, stream>>>(bsum, boff, nb2);
    k_scan<<<nb2, 256, 0, stream>>>(cnt, boff, rowptr, cursor, dinv, N, E);
    k_bucket<<<eb, 256, 0, stream>>>(src, dst, cursor, eidx, E);

    // input BN fold + projection
    k_colstats_x<<<1024, 256, 0, stream>>>(x, stats, stats + 128, N);
    k_fold<<<1, 256, 0, stream>>>(stats, bn_in_g, bn_in_b, Wp, bp, Wfold, bfold, invN);
    k_gemm1<<<nb, 256, 0, stream>>>(x, Wfold, bfold, H, N);

    // conv1
    k_gemm_scale<false><<<nb, 256, 0, stream>>>(H, W1, dinv, nullptr, nullptr, Bbuf, N);
    k_gather_finish<<<2048, 256, 0, stream>>>(Bbuf, rowptr, eidx, dinv, b1, H,
                                              stats + 256, stats + 320, N);
    k_ss<<<1, 64, 0, stream>>>(stats + 256, stats + 320, bn1_g, bn1_b, sc1, sh1, invN);

    // conv2
    k_gemm_scale<true><<<nb, 256, 0, stream>>>(H, W2, dinv, sc1, sh1, Bbuf, N);
    k_gather_finish<<<2048, 256, 0, stream>>>(Bbuf, rowptr, eidx, dinv, b2, H,
                                              stats + 384, stats + 448, N);
    k_ss<<<1, 64, 0, stream>>>(stats + 384, stats + 448, bn2_g, bn2_b, sc2, sh2, invN);

    k_final<<<(N * 16 + 255) / 256, 256, 0, stream>>>(H, sc2, sh2, H, N * 16);
}

// Round 3
// 692.835 us; speedup vs baseline: 1.6461x; 1.4421x over previous
//
#include <hip/hip_runtime.h>
#include <hip/hip_bf16.h>

#define EPS 1e-5f

__device__ __forceinline__ unsigned bf16_rtne(float f) {
    unsigned u = __float_as_uint(f);
    return (u + 0x7fffu + ((u >> 16) & 1u)) >> 16;
}
__device__ __forceinline__ unsigned pack2(float a, float b) {
    return bf16_rtne(a) | (bf16_rtne(b) << 16);
}
__device__ __forceinline__ float bf_lo(unsigned u) { return __uint_as_float(u << 16); }
__device__ __forceinline__ float bf_hi(unsigned u) { return __uint_as_float(u & 0xffff0000u); }

// ---------------- init: zero cnt[N] and stats[512] ----------------
__global__ void k_init(int* __restrict__ cnt, float* __restrict__ stats, int N) {
    int t = blockIdx.x * blockDim.x + threadIdx.x;
    if (t < N) cnt[t] = 0;
    if (t < 512) stats[t] = 0.0f;
}

// ---------------- histogram of dst ----------------
__global__ void k_hist(const int* __restrict__ dst, int* __restrict__ cnt, int E) {
    int t = blockIdx.x * blockDim.x + threadIdx.x;
    if (t < E) atomicAdd(&cnt[dst[t]], 1);
}

// ---------------- per-1024-block sums ----------------
__global__ void k_bsum(const int* __restrict__ cnt, int* __restrict__ bsum, int N) {
    __shared__ int ls[256];
    int tx = threadIdx.x;
    int i0 = blockIdx.x * 1024 + tx * 4;
    int s = 0;
#pragma unroll
    for (int j = 0; j < 4; j++)
        if (i0 + j < N) s += cnt[i0 + j];
    ls[tx] = s;
    __syncthreads();
    for (int st = 128; st > 0; st >>= 1) {
        if (tx < st) ls[tx] += ls[tx + st];
        __syncthreads();
    }
    if (tx == 0) bsum[blockIdx.x] = ls[0];
}

// ---------------- single-block exclusive scan of block sums (nb<=128) ----------------
__global__ void k_bscan(const int* __restrict__ bsum, int* __restrict__ boff, int nb) {
    int tx = threadIdx.x;  // 128 threads
    int v = (tx < nb) ? bsum[tx] : 0;
    int orig = v;
    int lane = tx & 63, wid = tx >> 6;
#pragma unroll
    for (int off = 1; off < 64; off <<= 1) {
        int u = __shfl_up(v, off);
        if (lane >= off) v += u;
    }
    __shared__ int w0;
    if (tx == 63) w0 = v;
    __syncthreads();
    if (wid == 1) v += w0;
    if (tx < nb) boff[tx] = v - orig;
}

// ------- per-block scan: rowptr, cursor, dinv = rsqrt(1+deg) -------
__global__ __launch_bounds__(256) void k_scan(const int* __restrict__ cnt,
                                              const int* __restrict__ boff,
                                              int* __restrict__ rowptr,
                                              int* __restrict__ cursor,
                                              float* __restrict__ dinv, int N, int E) {
    int tx = threadIdx.x;
    int i0 = blockIdx.x * 1024 + tx * 4;
    int c[4];
#pragma unroll
    for (int j = 0; j < 4; j++) c[j] = (i0 + j < N) ? cnt[i0 + j] : 0;
    int tot = c[0] + c[1] + c[2] + c[3];
    int lane = tx & 63, wid = tx >> 6;
    int v = tot;
#pragma unroll
    for (int off = 1; off < 64; off <<= 1) {
        int u = __shfl_up(v, off);
        if (lane >= off) v += u;
    }
    __shared__ int wsum[4];
    if (lane == 63) wsum[wid] = v;
    __syncthreads();
    int wbase = 0;
    for (int w = 0; w < wid; w++) wbase += wsum[w];
    int excl = boff[blockIdx.x] + wbase + (v - tot);
#pragma unroll
    for (int j = 0; j < 4; j++) {
        int i = i0 + j;
        if (i < N) {
            rowptr[i] = excl;
            cursor[i] = excl;
            dinv[i] = rsqrtf(1.0f + (float)c[j]);
            excl += c[j];
        }
    }
    if (blockIdx.x == 0 && tx == 0) rowptr[N] = E;
}

// ---------------- fill CSR buckets: eidx[slot] = src ----------------
__global__ void k_bucket(const int* __restrict__ src, const int* __restrict__ dst,
                         int* __restrict__ cursor, int* __restrict__ eidx, int E) {
    int t = blockIdx.x * blockDim.x + threadIdx.x;
    if (t < E) {
        int p = atomicAdd(&cursor[dst[t]], 1);
        eidx[p] = src[t];
    }
}

// ---------------- column stats of x [N x 128] ----------------
__global__ void k_colstats_x(const float* __restrict__ x, float* __restrict__ xsum,
                             float* __restrict__ xsq, int N) {
    __shared__ float ls[256], lq[256];
    int tx = threadIdx.x;
    int col = tx & 127, half = tx >> 7;
    float s = 0.f, q = 0.f;
    for (int r = blockIdx.x * 2 + half; r < N; r += gridDim.x * 2) {
        float v = x[(long long)r * 128 + col];
        s += v; q += v * v;
    }
    ls[tx] = s; lq[tx] = q;
    __syncthreads();
    if (half == 0) {
        s = ls[tx] + ls[tx + 128];
        q = lq[tx] + lq[tx + 128];
        atomicAdd(&xsum[col], s);
        atomicAdd(&xsq[col], q);
    }
}

// ---------------- fold BN_in into Wp -> Wfold, bfold ----------------
__global__ void k_fold(const float* __restrict__ stats, const float* __restrict__ g,
                       const float* __restrict__ b, const float* __restrict__ Wp,
                       const float* __restrict__ bp, float* __restrict__ Wfold,
                       float* __restrict__ bfold, float invN) {
    __shared__ float sc[128], sh[128];
    int tx = threadIdx.x;
    if (tx < 128) {
        float mu = stats[tx] * invN;
        float var = stats[128 + tx] * invN - mu * mu;
        float s = g[tx] * rsqrtf(var + EPS);
        sc[tx] = s;
        sh[tx] = b[tx] - mu * s;
    }
    __syncthreads();
    for (int i = tx; i < 128 * 64; i += 256) {
        int c = i >> 6;
        Wfold[i] = Wp[i] * sc[c];
    }
    if (tx < 64) {
        float acc = bp[tx];
        for (int c = 0; c < 128; c++) acc += sh[c] * Wp[c * 64 + tx];
        bfold[tx] = acc;
    }
}

// ---------------- gemm1: relu(x @ Wfold + bfold) -> H [N x 64] ----------------
__global__ __launch_bounds__(256) void k_gemm1(const float* __restrict__ x,
                                               const float* __restrict__ Wf,
                                               const float* __restrict__ bf,
                                               float* __restrict__ H, int N) {
    int r = blockIdx.x * blockDim.x + threadIdx.x;
    if (r >= N) return;
    float acc[64];
#pragma unroll
    for (int j = 0; j < 64; j++) acc[j] = 0.f;
    const float4* x4 = (const float4*)(x + (long long)r * 128);
    for (int c4 = 0; c4 < 32; c4++) {
        float4 xv = x4[c4];
#pragma unroll
        for (int q = 0; q < 4; q++) {
            float xs = (q == 0) ? xv.x : (q == 1) ? xv.y : (q == 2) ? xv.z : xv.w;
            const float* wrow = Wf + (c4 * 4 + q) * 64;
#pragma unroll
            for (int j = 0; j < 64; j++) acc[j] += xs * wrow[j];
        }
    }
    float4* out4 = (float4*)(H + (long long)r * 64);
#pragma unroll
    for (int i = 0; i < 16; i++) {
        float4 v;
        v.x = fmaxf(acc[4 * i + 0] + bf[4 * i + 0], 0.f);
        v.y = fmaxf(acc[4 * i + 1] + bf[4 * i + 1], 0.f);
        v.z = fmaxf(acc[4 * i + 2] + bf[4 * i + 2], 0.f);
        v.w = fmaxf(acc[4 * i + 3] + bf[4 * i + 3], 0.f);
        out4[i] = v;
    }
}

// ------- gemm_scale: hs = (optional BN+relu(In)) @ W * dinv[row] -> Bpk (bf16 packed) -------
template <bool BNRELU>
__global__ __launch_bounds__(256) void k_gemm_scale(
    const float* __restrict__ In, const float* __restrict__ W,
    const float* __restrict__ dinv, const float* __restrict__ sc,
    const float* __restrict__ sh, unsigned* __restrict__ Bpk, int N) {
    int r = blockIdx.x * blockDim.x + threadIdx.x;
    if (r >= N) return;
    float acc[64];
#pragma unroll
    for (int j = 0; j < 64; j++) acc[j] = 0.f;
    const float4* in4 = (const float4*)(In + (long long)r * 64);
    for (int c4 = 0; c4 < 16; c4++) {
        float4 xv = in4[c4];
        if (BNRELU) {
            int cb = c4 * 4;
            xv.x = fmaxf(xv.x * sc[cb + 0] + sh[cb + 0], 0.f);
            xv.y = fmaxf(xv.y * sc[cb + 1] + sh[cb + 1], 0.f);
            xv.z = fmaxf(xv.z * sc[cb + 2] + sh[cb + 2], 0.f);
            xv.w = fmaxf(xv.w * sc[cb + 3] + sh[cb + 3], 0.f);
        }
#pragma unroll
        for (int q = 0; q < 4; q++) {
            float xs = (q == 0) ? xv.x : (q == 1) ? xv.y : (q == 2) ? xv.z : xv.w;
            const float* wrow = W + (c4 * 4 + q) * 64;
#pragma unroll
            for (int j = 0; j < 64; j++) acc[j] += xs * wrow[j];
        }
    }
    float dv = dinv[r];
    uint4* b4 = (uint4*)(Bpk + (long long)r * 32);
#pragma unroll
    for (int i = 0; i < 8; i++) {
        uint4 v;
        v.x = pack2(acc[8 * i + 0] * dv, acc[8 * i + 1] * dv);
        v.y = pack2(acc[8 * i + 2] * dv, acc[8 * i + 3] * dv);
        v.z = pack2(acc[8 * i + 4] * dv, acc[8 * i + 5] * dv);
        v.w = pack2(acc[8 * i + 6] * dv, acc[8 * i + 7] * dv);
        b4[i] = v;
    }
}

// ------- gather+finish: out[d] = dinv[d]*(hs[d] + sum_nbr hs[s]) + b; stats -------
// 8 lanes per node (uint4 = 8 bf16 feats each), 32 nodes per 256-block.
__global__ __launch_bounds__(256) void k_gather_finish(
    const uint4* __restrict__ B, const int* __restrict__ rowptr,
    const int* __restrict__ eidx, const float* __restrict__ dinv,
    const float* __restrict__ bias, float* __restrict__ Out,
    float* __restrict__ ssum, float* __restrict__ ssq, int N) {
    int tx = threadIdx.x;
    int g = tx >> 3;   // node slot in block (32 per block)
    int l = tx & 7;    // feature octet
    int d = blockIdx.x * 32 + g;

    float acc[8], s[8], q[8];
#pragma unroll
    for (int j = 0; j < 8; j++) { s[j] = 0.f; q[j] = 0.f; }

    if (d < N) {
        int beg = rowptr[d], end = rowptr[d + 1];
        // self term
        uint4 v0 = B[(long long)d * 8 + l];
        acc[0] = bf_lo(v0.x); acc[1] = bf_hi(v0.x);
        acc[2] = bf_lo(v0.y); acc[3] = bf_hi(v0.y);
        acc[4] = bf_lo(v0.z); acc[5] = bf_hi(v0.z);
        acc[6] = bf_lo(v0.w); acc[7] = bf_hi(v0.w);
        int k = beg;
        for (; k + 3 < end; k += 4) {
            int sA = eidx[k], sB = eidx[k + 1], sC = eidx[k + 2], sD = eidx[k + 3];
            uint4 a = B[(long long)sA * 8 + l];
            uint4 b = B[(long long)sB * 8 + l];
            uint4 c = B[(long long)sC * 8 + l];
            uint4 e = B[(long long)sD * 8 + l];
            acc[0] += bf_lo(a.x) + bf_lo(b.x) + bf_lo(c.x) + bf_lo(e.x);
            acc[1] += bf_hi(a.x) + bf_hi(b.x) + bf_hi(c.x) + bf_hi(e.x);
            acc[2] += bf_lo(a.y) + bf_lo(b.y) + bf_lo(c.y) + bf_lo(e.y);
            acc[3] += bf_hi(a.y) + bf_hi(b.y) + bf_hi(c.y) + bf_hi(e.y);
            acc[4] += bf_lo(a.z) + bf_lo(b.z) + bf_lo(c.z) + bf_lo(e.z);
            acc[5] += bf_hi(a.z) + bf_hi(b.z) + bf_hi(c.z) + bf_hi(e.z);
            acc[6] += bf_lo(a.w) + bf_lo(b.w) + bf_lo(c.w) + bf_lo(e.w);
            acc[7] += bf_hi(a.w) + bf_hi(b.w) + bf_hi(c.w) + bf_hi(e.w);
        }
        for (; k < end; k++) {
            int sA = eidx[k];
            uint4 a = B[(long long)sA * 8 + l];
            acc[0] += bf_lo(a.x); acc[1] += bf_hi(a.x);
            acc[2] += bf_lo(a.y); acc[3] += bf_hi(a.y);
            acc[4] += bf_lo(a.z); acc[5] += bf_hi(a.z);
            acc[6] += bf_lo(a.w); acc[7] += bf_hi(a.w);
        }
        float dv = dinv[d];
        float4 o0, o1;
        float* op = &o0.x;
#pragma unroll
        for (int j = 0; j < 8; j++) {
            float v = acc[j] * dv + bias[8 * l + j];
            ((j < 4) ? (&o0.x)[j] : (&o1.x)[j - 4]) = v;
            s[j] += v; q[j] += v * v;
        }
        (void)op;
        float4* outp = (float4*)(Out + (long long)d * 64 + 8 * l);
        outp[0] = o0;
        outp[1] = o1;
    }

    __shared__ float ls[256][8], lq[256][8];
#pragma unroll
    for (int j = 0; j < 8; j++) { ls[tx][j] = s[j]; lq[tx][j] = q[j]; }
    __syncthreads();
    if (tx < 64) {
        int l0 = tx >> 3, j = tx & 7;  // feature f = 8*l0 + j
        float S = 0.f, Q = 0.f;
        for (int gg = 0; gg < 32; gg++) {
            S += ls[gg * 8 + l0][j];
            Q += lq[gg * 8 + l0][j];
        }
        atomicAdd(&ssum[8 * l0 + j], S);
        atomicAdd(&ssq[8 * l0 + j], Q);
    }
}

// ---------------- compute BN scale/shift from stats ----------------
__global__ void k_ss(const float* __restrict__ ssum, const float* __restrict__ ssq,
                     const float* __restrict__ g, const float* __restrict__ b,
                     float* __restrict__ sc, float* __restrict__ sh, float invN) {
    int t = threadIdx.x;
    if (t < 64) {
        float mu = ssum[t] * invN;
        float var = ssq[t] * invN - mu * mu;
        float s = g[t] * rsqrtf(var + EPS);
        sc[t] = s;
        sh[t] = b[t] - mu * s;
    }
}

// ---------------- final elementwise BN apply (in-place safe) ----------------
__global__ void k_final(const float* __restrict__ In, const float* __restrict__ sc,
                        const float* __restrict__ sh, float* __restrict__ out, int total4) {
    int t = blockIdx.x * blockDim.x + threadIdx.x;
    if (t < total4) {
        float4 v = ((const float4*)In)[t];
        int j = (t * 4) & 63;
        v.x = v.x * sc[j + 0] + sh[j + 0];
        v.y = v.y * sc[j + 1] + sh[j + 1];
        v.z = v.z * sc[j + 2] + sh[j + 2];
        v.w = v.w * sc[j + 3] + sh[j + 3];
        ((float4*)out)[t] = v;
    }
}

extern "C" void kernel_launch(void* const* d_in, const int* in_sizes, int n_in,
                              void* d_out, int out_size, void* d_ws, size_t ws_size,
                              hipStream_t stream) {
    const float* x       = (const float*)d_in[0];
    const int*   ei      = (const int*)d_in[1];
    const float* bn_in_g = (const float*)d_in[2];
    const float* bn_in_b = (const float*)d_in[3];
    const float* Wp      = (const float*)d_in[4];
    const float* bp      = (const float*)d_in[5];
    const float* W1      = (const float*)d_in[6];
    const float* b1      = (const float*)d_in[7];
    const float* bn1_g   = (const float*)d_in[8];
    const float* bn1_b   = (const float*)d_in[9];
    const float* W2      = (const float*)d_in[10];
    const float* b2      = (const float*)d_in[11];
    const float* bn2_g   = (const float*)d_in[12];
    const float* bn2_b   = (const float*)d_in[13];

    int N = in_sizes[0] / 128;
    int E = in_sizes[1] / 2;
    const int* src = ei;
    const int* dst = ei + E;

    long long Npad = ((long long)N + 128) & ~127LL;  // >= N+1, 128-aligned
    int*   cnt    = (int*)d_ws;
    int*   rowptr = cnt + Npad;
    int*   cursor = rowptr + Npad;
    float* dinv   = (float*)(cursor + Npad);
    float* stats  = dinv + Npad;          // 512
    float* sc1    = stats + 512;          // 64
    float* sh1    = sc1 + 64;
    float* sc2    = sh1 + 64;
    float* sh2    = sc2 + 64;
    float* Wfold  = sh2 + 64;             // 8192
    float* bfold  = Wfold + 8192;         // 64
    int*   bsum   = (int*)(bfold + 64);   // 128
    int*   boff   = bsum + 128;           // 128
    int*   eidx   = boff + 128;           // E
    unsigned* Bpk = (unsigned*)(eidx + ((E + 127) & ~127)); // N*32 (bf16 packed)
    float* H      = (float*)d_out;        // N*64 intermediate + final out

    int nb  = (N + 255) / 256;
    int nb2 = (N + 1023) / 1024;
    int eb  = (E + 255) / 256;
    int gb  = (N + 31) / 32;
    float invN = 1.0f / (float)N;

    // CSR build
    k_init<<<nb, 256, 0, stream>>>(cnt, stats, N);
    k_hist<<<eb, 256, 0, stream>>>(dst, cnt, E);
    k_bsum<<<nb2, 256, 0, stream>>>(cnt, bsum, N);
    k_bscan<<<1, 128, 0, stream>>>(bsum, boff, nb2);
    k_scan<<<nb2, 256, 0, stream>>>(cnt, boff, rowptr, cursor, dinv, N, E);
    k_bucket<<<eb, 256, 0, stream>>>(src, dst, cursor, eidx, E);

    // input BN fold + projection
    k_colstats_x<<<1024, 256, 0, stream>>>(x, stats, stats + 128, N);
    k_fold<<<1, 256, 0, stream>>>(stats, bn_in_g, bn_in_b, Wp, bp, Wfold, bfold, invN);
    k_gemm1<<<nb, 256, 0, stream>>>(x, Wfold, bfold, H, N);

    // conv1
    k_gemm_scale<false><<<nb, 256, 0, stream>>>(H, W1, dinv, nullptr, nullptr, Bpk, N);
    k_gather_finish<<<gb, 256, 0, stream>>>((const uint4*)Bpk, rowptr, eidx, dinv, b1, H,
                                            stats + 256, stats + 320, N);
    k_ss<<<1, 64, 0, stream>>>(stats + 256, stats + 320, bn1_g, bn1_b, sc1, sh1, invN);

    // conv2
    k_gemm_scale<true><<<nb, 256, 0, stream>>>(H, W2, dinv, sc1, sh1, Bpk, N);
    k_gather_finish<<<gb, 256, 0, stream>>>((const uint4*)Bpk, rowptr, eidx, dinv, b2, H,
                                            stats + 384, stats + 448, N);
    k_ss<<<1, 64, 0, stream>>>(stats + 384, stats + 448, bn2_g, bn2_b, sc2, sh2, invN);

    k_final<<<(N * 16 + 255) / 256, 256, 0, stream>>>(H, sc2, sh2, H, N * 16);
}

// Round 4
// 580.154 us; speedup vs baseline: 1.9659x; 1.1942x over previous
//
#include <hip/hip_runtime.h>
#include <hip/hip_bf16.h>

#define EPS 1e-5f

__device__ __forceinline__ unsigned bf16_rtne(float f) {
    unsigned u = __float_as_uint(f);
    return (u + 0x7fffu + ((u >> 16) & 1u)) >> 16;
}
__device__ __forceinline__ unsigned pack2(float a, float b) {
    return bf16_rtne(a) | (bf16_rtne(b) << 16);
}
__device__ __forceinline__ float bf_lo(unsigned u) { return __uint_as_float(u << 16); }
__device__ __forceinline__ float bf_hi(unsigned u) { return __uint_as_float(u & 0xffff0000u); }

// ---------------- zero coarse counters + stats ----------------
__global__ void k_zero(int* __restrict__ cc, float* __restrict__ stats, int NB) {
    int t = threadIdx.x;  // 512 threads, 1 block
    if (t < NB) cc[t] = 0;
    if (t < 512) stats[t] = 0.0f;
}

// ---------------- coarse histogram of dst>>8 (LDS-aggregated) ----------------
__global__ __launch_bounds__(256) void k_chist(const int* __restrict__ dst,
                                               int* __restrict__ cc, int E, int NB) {
    __shared__ int h[512];
    int tx = threadIdx.x;
    for (int i = tx; i < NB; i += 256) h[i] = 0;
    __syncthreads();
    int stride = gridDim.x * 256;
    for (int e = blockIdx.x * 256 + tx; e < E; e += stride)
        atomicAdd(&h[dst[e] >> 8], 1);
    __syncthreads();
    for (int i = tx; i < NB; i += 256)
        if (h[i]) atomicAdd(&cc[i], h[i]);
}

// ---------------- scan coarse counts (1 block, 512 threads, NB<=512) ----------------
__global__ void k_cscan(const int* __restrict__ cc, int* __restrict__ coff,
                        int* __restrict__ cur, int NB, int E) {
    __shared__ int ls[512];
    int tx = threadIdx.x;
    int v = (tx < NB) ? cc[tx] : 0;
    ls[tx] = v;
    __syncthreads();
    for (int off = 1; off < 512; off <<= 1) {
        int u = (tx >= off) ? ls[tx - off] : 0;
        __syncthreads();
        ls[tx] += u;
        __syncthreads();
    }
    int excl = ls[tx] - v;
    if (tx < NB) { coff[tx] = excl; cur[tx] = excl; }
    if (tx == NB - 1) coff[NB] = excl + v;
}

// ------- partition edges into coarse buckets; pack (src<<8)|(dst&255) -------
#define PCHUNK 4096
__global__ __launch_bounds__(256) void k_partition(const int* __restrict__ src,
                                                   const int* __restrict__ dst,
                                                   int* __restrict__ cursor,
                                                   unsigned* __restrict__ packbuf,
                                                   int E, int NB) {
    __shared__ int h[512], base[512];
    int tx = threadIdx.x;
    int e0 = blockIdx.x * PCHUNK;
    int e1 = min(e0 + PCHUNK, E);
    for (int i = tx; i < NB; i += 256) h[i] = 0;
    __syncthreads();
    for (int e = e0 + tx; e < e1; e += 256)
        atomicAdd(&h[dst[e] >> 8], 1);
    __syncthreads();
    for (int i = tx; i < NB; i += 256) {
        int c = h[i];
        base[i] = c ? atomicAdd(&cursor[i], c) : 0;
        h[i] = 0;  // reuse as local cursor
    }
    __syncthreads();
    for (int e = e0 + tx; e < e1; e += 256) {
        int d = dst[e];
        int b = d >> 8;
        int p = base[b] + atomicAdd(&h[b], 1);
        packbuf[p] = ((unsigned)src[e] << 8) | (unsigned)(d & 255);
    }
}

// ------- per-bucket CSR build: local hist, scan -> rowptr/dinv, scatter eidx -------
__global__ __launch_bounds__(256) void k_build(const unsigned* __restrict__ packbuf,
                                               const int* __restrict__ coff,
                                               int* __restrict__ rowptr,
                                               float* __restrict__ dinv,
                                               int* __restrict__ eidx, int N, int E) {
    __shared__ int cnt[256], loff[256], wsum[4];
    int b = blockIdx.x;
    int tx = threadIdx.x;
    int beg = coff[b], end = coff[b + 1];
    cnt[tx] = 0;
    __syncthreads();
    for (int e = beg + tx; e < end; e += 256)
        atomicAdd(&cnt[packbuf[e] & 255u], 1);
    __syncthreads();
    int c = cnt[tx];
    int lane = tx & 63, wid = tx >> 6;
    int v = c;
#pragma unroll
    for (int off = 1; off < 64; off <<= 1) {
        int u = __shfl_up(v, off);
        if (lane >= off) v += u;
    }
    if (lane == 63) wsum[wid] = v;
    __syncthreads();
    int wbase = 0;
    for (int w = 0; w < wid; w++) wbase += wsum[w];
    int excl = wbase + v - c;
    loff[tx] = excl;  // local cursor start
    int node = b * 256 + tx;
    if (node < N) {
        rowptr[node] = beg + excl;
        dinv[node] = rsqrtf(1.0f + (float)c);
    }
    if (b == 0 && tx == 0) rowptr[N] = E;
    __syncthreads();
    for (int e = beg + tx; e < end; e += 256) {
        unsigned pk = packbuf[e];
        int pos = atomicAdd(&loff[pk & 255u], 1);
        eidx[beg + pos] = (int)(pk >> 8);
    }
}

// ---------------- column stats of x [N x 128] ----------------
__global__ void k_colstats_x(const float* __restrict__ x, float* __restrict__ xsum,
                             float* __restrict__ xsq, int N) {
    __shared__ float ls[256], lq[256];
    int tx = threadIdx.x;
    int col = tx & 127, half = tx >> 7;
    float s = 0.f, q = 0.f;
    for (int r = blockIdx.x * 2 + half; r < N; r += gridDim.x * 2) {
        float v = x[(long long)r * 128 + col];
        s += v; q += v * v;
    }
    ls[tx] = s; lq[tx] = q;
    __syncthreads();
    if (half == 0) {
        s = ls[tx] + ls[tx + 128];
        q = lq[tx] + lq[tx + 128];
        atomicAdd(&xsum[col], s);
        atomicAdd(&xsq[col], q);
    }
}

// ---------------- fold BN_in into Wp -> Wfold, bfold ----------------
__global__ void k_fold(const float* __restrict__ stats, const float* __restrict__ g,
                       const float* __restrict__ b, const float* __restrict__ Wp,
                       const float* __restrict__ bp, float* __restrict__ Wfold,
                       float* __restrict__ bfold, float invN) {
    __shared__ float sc[128], sh[128];
    int tx = threadIdx.x;
    if (tx < 128) {
        float mu = stats[tx] * invN;
        float var = stats[128 + tx] * invN - mu * mu;
        float s = g[tx] * rsqrtf(var + EPS);
        sc[tx] = s;
        sh[tx] = b[tx] - mu * s;
    }
    __syncthreads();
    for (int i = tx; i < 128 * 64; i += 256) {
        int c = i >> 6;
        Wfold[i] = Wp[i] * sc[c];
    }
    if (tx < 64) {
        float acc = bp[tx];
        for (int c = 0; c < 128; c++) acc += sh[c] * Wp[c * 64 + tx];
        bfold[tx] = acc;
    }
}

// ---------------- gemm1: relu(x @ Wfold + bfold) -> H [N x 64] ----------------
__global__ __launch_bounds__(256) void k_gemm1(const float* __restrict__ x,
                                               const float* __restrict__ Wf,
                                               const float* __restrict__ bf,
                                               float* __restrict__ H, int N) {
    int r = blockIdx.x * blockDim.x + threadIdx.x;
    if (r >= N) return;
    float acc[64];
#pragma unroll
    for (int j = 0; j < 64; j++) acc[j] = 0.f;
    const float4* x4 = (const float4*)(x + (long long)r * 128);
    for (int c4 = 0; c4 < 32; c4++) {
        float4 xv = x4[c4];
#pragma unroll
        for (int q = 0; q < 4; q++) {
            float xs = (q == 0) ? xv.x : (q == 1) ? xv.y : (q == 2) ? xv.z : xv.w;
            const float* wrow = Wf + (c4 * 4 + q) * 64;
#pragma unroll
            for (int j = 0; j < 64; j++) acc[j] += xs * wrow[j];
        }
    }
    float4* out4 = (float4*)(H + (long long)r * 64);
#pragma unroll
    for (int i = 0; i < 16; i++) {
        float4 v;
        v.x = fmaxf(acc[4 * i + 0] + bf[4 * i + 0], 0.f);
        v.y = fmaxf(acc[4 * i + 1] + bf[4 * i + 1], 0.f);
        v.z = fmaxf(acc[4 * i + 2] + bf[4 * i + 2], 0.f);
        v.w = fmaxf(acc[4 * i + 3] + bf[4 * i + 3], 0.f);
        out4[i] = v;
    }
}

// ------- gemm_scale: hs = (optional BN+relu(In)) @ W * dinv[row] -> Bpk (bf16) -------
template <bool BNRELU>
__global__ __launch_bounds__(256) void k_gemm_scale(
    const float* __restrict__ In, const float* __restrict__ W,
    const float* __restrict__ dinv, const float* __restrict__ sc,
    const float* __restrict__ sh, unsigned* __restrict__ Bpk, int N) {
    int r = blockIdx.x * blockDim.x + threadIdx.x;
    if (r >= N) return;
    float acc[64];
#pragma unroll
    for (int j = 0; j < 64; j++) acc[j] = 0.f;
    const float4* in4 = (const float4*)(In + (long long)r * 64);
    for (int c4 = 0; c4 < 16; c4++) {
        float4 xv = in4[c4];
        if (BNRELU) {
            int cb = c4 * 4;
            xv.x = fmaxf(xv.x * sc[cb + 0] + sh[cb + 0], 0.f);
            xv.y = fmaxf(xv.y * sc[cb + 1] + sh[cb + 1], 0.f);
            xv.z = fmaxf(xv.z * sc[cb + 2] + sh[cb + 2], 0.f);
            xv.w = fmaxf(xv.w * sc[cb + 3] + sh[cb + 3], 0.f);
        }
#pragma unroll
        for (int q = 0; q < 4; q++) {
            float xs = (q == 0) ? xv.x : (q == 1) ? xv.y : (q == 2) ? xv.z : xv.w;
            const float* wrow = W + (c4 * 4 + q) * 64;
#pragma unroll
            for (int j = 0; j < 64; j++) acc[j] += xs * wrow[j];
        }
    }
    float dv = dinv[r];
    uint4* b4 = (uint4*)(Bpk + (long long)r * 32);
#pragma unroll
    for (int i = 0; i < 8; i++) {
        uint4 v;
        v.x = pack2(acc[8 * i + 0] * dv, acc[8 * i + 1] * dv);
        v.y = pack2(acc[8 * i + 2] * dv, acc[8 * i + 3] * dv);
        v.z = pack2(acc[8 * i + 4] * dv, acc[8 * i + 5] * dv);
        v.w = pack2(acc[8 * i + 6] * dv, acc[8 * i + 7] * dv);
        b4[i] = v;
    }
}

// ------- gather+finish: out[d] = dinv[d]*(hs[d] + sum_nbr hs[s]) + b; stats -------
__global__ __launch_bounds__(256) void k_gather_finish(
    const uint4* __restrict__ B, const int* __restrict__ rowptr,
    const int* __restrict__ eidx, const float* __restrict__ dinv,
    const float* __restrict__ bias, float* __restrict__ Out,
    float* __restrict__ ssum, float* __restrict__ ssq, int N) {
    int tx = threadIdx.x;
    int g = tx >> 3;   // node slot in block (32 per block)
    int l = tx & 7;    // feature octet
    int d = blockIdx.x * 32 + g;

    float acc[8], s[8], q[8];
#pragma unroll
    for (int j = 0; j < 8; j++) { s[j] = 0.f; q[j] = 0.f; }

    if (d < N) {
        int beg = rowptr[d], end = rowptr[d + 1];
        uint4 v0 = B[(long long)d * 8 + l];
        acc[0] = bf_lo(v0.x); acc[1] = bf_hi(v0.x);
        acc[2] = bf_lo(v0.y); acc[3] = bf_hi(v0.y);
        acc[4] = bf_lo(v0.z); acc[5] = bf_hi(v0.z);
        acc[6] = bf_lo(v0.w); acc[7] = bf_hi(v0.w);
        int k = beg;
        for (; k + 3 < end; k += 4) {
            int sA = eidx[k], sB = eidx[k + 1], sC = eidx[k + 2], sD = eidx[k + 3];
            uint4 a = B[(long long)sA * 8 + l];
            uint4 b = B[(long long)sB * 8 + l];
            uint4 c = B[(long long)sC * 8 + l];
            uint4 e = B[(long long)sD * 8 + l];
            acc[0] += bf_lo(a.x) + bf_lo(b.x) + bf_lo(c.x) + bf_lo(e.x);
            acc[1] += bf_hi(a.x) + bf_hi(b.x) + bf_hi(c.x) + bf_hi(e.x);
            acc[2] += bf_lo(a.y) + bf_lo(b.y) + bf_lo(c.y) + bf_lo(e.y);
            acc[3] += bf_hi(a.y) + bf_hi(b.y) + bf_hi(c.y) + bf_hi(e.y);
            acc[4] += bf_lo(a.z) + bf_lo(b.z) + bf_lo(c.z) + bf_lo(e.z);
            acc[5] += bf_hi(a.z) + bf_hi(b.z) + bf_hi(c.z) + bf_hi(e.z);
            acc[6] += bf_lo(a.w) + bf_lo(b.w) + bf_lo(c.w) + bf_lo(e.w);
            acc[7] += bf_hi(a.w) + bf_hi(b.w) + bf_hi(c.w) + bf_hi(e.w);
        }
        for (; k < end; k++) {
            int sA = eidx[k];
            uint4 a = B[(long long)sA * 8 + l];
            acc[0] += bf_lo(a.x); acc[1] += bf_hi(a.x);
            acc[2] += bf_lo(a.y); acc[3] += bf_hi(a.y);
            acc[4] += bf_lo(a.z); acc[5] += bf_hi(a.z);
            acc[6] += bf_lo(a.w); acc[7] += bf_hi(a.w);
        }
        float dv = dinv[d];
        float4 o0, o1;
#pragma unroll
        for (int j = 0; j < 8; j++) {
            float v = acc[j] * dv + bias[8 * l + j];
            ((j < 4) ? (&o0.x)[j] : (&o1.x)[j - 4]) = v;
            s[j] += v; q[j] += v * v;
        }
        float4* outp = (float4*)(Out + (long long)d * 64 + 8 * l);
        outp[0] = o0;
        outp[1] = o1;
    }

    __shared__ float ls[256][8], lq[256][8];
#pragma unroll
    for (int j = 0; j < 8; j++) { ls[tx][j] = s[j]; lq[tx][j] = q[j]; }
    __syncthreads();
    if (tx < 64) {
        int l0 = tx >> 3, j = tx & 7;  // feature f = 8*l0 + j
        float S = 0.f, Q = 0.f;
        for (int gg = 0; gg < 32; gg++) {
            S += ls[gg * 8 + l0][j];
            Q += lq[gg * 8 + l0][j];
        }
        atomicAdd(&ssum[8 * l0 + j], S);
        atomicAdd(&ssq[8 * l0 + j], Q);
    }
}

// ---------------- compute BN scale/shift from stats ----------------
__global__ void k_ss(const float* __restrict__ ssum, const float* __restrict__ ssq,
                     const float* __restrict__ g, const float* __restrict__ b,
                     float* __restrict__ sc, float* __restrict__ sh, float invN) {
    int t = threadIdx.x;
    if (t < 64) {
        float mu = ssum[t] * invN;
        float var = ssq[t] * invN - mu * mu;
        float s = g[t] * rsqrtf(var + EPS);
        sc[t] = s;
        sh[t] = b[t] - mu * s;
    }
}

// ---------------- final elementwise BN apply (in-place safe) ----------------
__global__ void k_final(const float* __restrict__ In, const float* __restrict__ sc,
                        const float* __restrict__ sh, float* __restrict__ out, int total4) {
    int t = blockIdx.x * blockDim.x + threadIdx.x;
    if (t < total4) {
        float4 v = ((const float4*)In)[t];
        int j = (t * 4) & 63;
        v.x = v.x * sc[j + 0] + sh[j + 0];
        v.y = v.y * sc[j + 1] + sh[j + 1];
        v.z = v.z * sc[j + 2] + sh[j + 2];
        v.w = v.w * sc[j + 3] + sh[j + 3];
        ((float4*)out)[t] = v;
    }
}

extern "C" void kernel_launch(void* const* d_in, const int* in_sizes, int n_in,
                              void* d_out, int out_size, void* d_ws, size_t ws_size,
                              hipStream_t stream) {
    const float* x       = (const float*)d_in[0];
    const int*   ei      = (const int*)d_in[1];
    const float* bn_in_g = (const float*)d_in[2];
    const float* bn_in_b = (const float*)d_in[3];
    const float* Wp      = (const float*)d_in[4];
    const float* bp      = (const float*)d_in[5];
    const float* W1      = (const float*)d_in[6];
    const float* b1      = (const float*)d_in[7];
    const float* bn1_g   = (const float*)d_in[8];
    const float* bn1_b   = (const float*)d_in[9];
    const float* W2      = (const float*)d_in[10];
    const float* b2      = (const float*)d_in[11];
    const float* bn2_g   = (const float*)d_in[12];
    const float* bn2_b   = (const float*)d_in[13];

    int N = in_sizes[0] / 128;
    int E = in_sizes[1] / 2;
    const int* src = ei;
    const int* dst = ei + E;
    int NB = (N + 255) >> 8;  // coarse buckets (<=512); requires N < 2^24

    long long Npad = ((long long)N + 128) & ~127LL;
    int*   cc     = (int*)d_ws;           // 512 coarse counts
    int*   coff   = cc + 512;             // 513 coarse offsets
    int*   cur    = coff + 640;           // 512 coarse cursors
    int*   rowptr = cur + 512;            // Npad
    float* dinv   = (float*)(rowptr + Npad);
    float* stats  = dinv + Npad;          // 512
    float* sc1    = stats + 512;
    float* sh1    = sc1 + 64;
    float* sc2    = sh1 + 64;
    float* sh2    = sc2 + 64;
    float* Wfold  = sh2 + 64;             // 8192
    float* bfold  = Wfold + 8192;         // 64
    unsigned* packbuf = (unsigned*)(bfold + 64);          // E
    int*   eidx   = (int*)(packbuf + ((E + 127) & ~127)); // E
    unsigned* Bpk = (unsigned*)(eidx + ((E + 127) & ~127)); // N*32
    float* H      = (float*)d_out;        // N*64 intermediate + final out

    int nb = (N + 255) / 256;
    int gb = (N + 31) / 32;
    float invN = 1.0f / (float)N;

    // CSR build via two-level radix partition
    k_zero<<<1, 512, 0, stream>>>(cc, stats, NB);
    k_chist<<<256, 256, 0, stream>>>(dst, cc, E, NB);
    k_cscan<<<1, 512, 0, stream>>>(cc, coff, cur, NB, E);
    k_partition<<<(E + PCHUNK - 1) / PCHUNK, 256, 0, stream>>>(src, dst, cur, packbuf, E, NB);
    k_build<<<NB, 256, 0, stream>>>(packbuf, coff, rowptr, dinv, eidx, N, E);

    // input BN fold + projection
    k_colstats_x<<<1024, 256, 0, stream>>>(x, stats, stats + 128, N);
    k_fold<<<1, 256, 0, stream>>>(stats, bn_in_g, bn_in_b, Wp, bp, Wfold, bfold, invN);
    k_gemm1<<<nb, 256, 0, stream>>>(x, Wfold, bfold, H, N);

    // conv1
    k_gemm_scale<false><<<nb, 256, 0, stream>>>(H, W1, dinv, nullptr, nullptr, Bpk, N);
    k_gather_finish<<<gb, 256, 0, stream>>>((const uint4*)Bpk, rowptr, eidx, dinv, b1, H,
                                            stats + 256, stats + 320, N);
    k_ss<<<1, 64, 0, stream>>>(stats + 256, stats + 320, bn1_g, bn1_b, sc1, sh1, invN);

    // conv2
    k_gemm_scale<true><<<nb, 256, 0, stream>>>(H, W2, dinv, sc1, sh1, Bpk, N);
    k_gather_finish<<<gb, 256, 0, stream>>>((const uint4*)Bpk, rowptr, eidx, dinv, b2, H,
                                            stats + 384, stats + 448, N);
    k_ss<<<1, 64, 0, stream>>>(stats + 384, stats + 448, bn2_g, bn2_b, sc2, sh2, invN);

    k_final<<<(N * 16 + 255) / 256, 256, 0, stream>>>(H, sc2, sh2, H, N * 16);
}

// Round 5
// 566.830 us; speedup vs baseline: 2.0121x; 1.0235x over previous
//
#include <hip/hip_runtime.h>
#include <hip/hip_bf16.h>

#define EPS 1e-5f

__device__ __forceinline__ unsigned bf16_rtne(float f) {
    unsigned u = __float_as_uint(f);
    return (u + 0x7fffu + ((u >> 16) & 1u)) >> 16;
}
__device__ __forceinline__ unsigned pack2(float a, float b) {
    return bf16_rtne(a) | (bf16_rtne(b) << 16);
}
__device__ __forceinline__ float bf_lo(unsigned u) { return __uint_as_float(u << 16); }
__device__ __forceinline__ float bf_hi(unsigned u) { return __uint_as_float(u & 0xffff0000u); }

__device__ __forceinline__ void acc_row(float* acc, uint4 a) {
    acc[0] += bf_lo(a.x); acc[1] += bf_hi(a.x);
    acc[2] += bf_lo(a.y); acc[3] += bf_hi(a.y);
    acc[4] += bf_lo(a.z); acc[5] += bf_hi(a.z);
    acc[6] += bf_lo(a.w); acc[7] += bf_hi(a.w);
}

// ---------------- zero coarse counters + stats ----------------
__global__ void k_zero(int* __restrict__ cc, float* __restrict__ stats, int NB) {
    int t = threadIdx.x;  // 512 threads, 1 block
    if (t < NB) cc[t] = 0;
    if (t < 512) stats[t] = 0.0f;
}

// ---------------- coarse histogram of dst>>8 (LDS-aggregated) ----------------
__global__ __launch_bounds__(256) void k_chist(const int* __restrict__ dst,
                                               int* __restrict__ cc, int E, int NB) {
    __shared__ int h[512];
    int tx = threadIdx.x;
    for (int i = tx; i < NB; i += 256) h[i] = 0;
    __syncthreads();
    int stride = gridDim.x * 256;
    for (int e = blockIdx.x * 256 + tx; e < E; e += stride)
        atomicAdd(&h[dst[e] >> 8], 1);
    __syncthreads();
    for (int i = tx; i < NB; i += 256)
        if (h[i]) atomicAdd(&cc[i], h[i]);
}

// ---------------- scan coarse counts (1 block, 512 threads, NB<=512) ----------------
__global__ void k_cscan(const int* __restrict__ cc, int* __restrict__ coff,
                        int* __restrict__ cur, int NB, int E) {
    __shared__ int ls[512];
    int tx = threadIdx.x;
    int v = (tx < NB) ? cc[tx] : 0;
    ls[tx] = v;
    __syncthreads();
    for (int off = 1; off < 512; off <<= 1) {
        int u = (tx >= off) ? ls[tx - off] : 0;
        __syncthreads();
        ls[tx] += u;
        __syncthreads();
    }
    int excl = ls[tx] - v;
    if (tx < NB) { coff[tx] = excl; cur[tx] = excl; }
    if (tx == NB - 1) coff[NB] = excl + v;
}

// ------- partition edges into coarse buckets; pack (src<<8)|(dst&255) -------
#define PCHUNK 2048
__global__ __launch_bounds__(256) void k_partition(const int* __restrict__ src,
                                                   const int* __restrict__ dst,
                                                   int* __restrict__ cursor,
                                                   unsigned* __restrict__ packbuf,
                                                   int E, int NB) {
    __shared__ int h[512], base[512];
    int tx = threadIdx.x;
    int e0 = blockIdx.x * PCHUNK;
    int e1 = min(e0 + PCHUNK, E);
    for (int i = tx; i < NB; i += 256) h[i] = 0;
    __syncthreads();
    for (int e = e0 + tx; e < e1; e += 256)
        atomicAdd(&h[dst[e] >> 8], 1);
    __syncthreads();
    for (int i = tx; i < NB; i += 256) {
        int c = h[i];
        base[i] = c ? atomicAdd(&cursor[i], c) : 0;
        h[i] = 0;  // reuse as local cursor
    }
    __syncthreads();
    for (int e = e0 + tx; e < e1; e += 256) {
        int d = dst[e];
        int b = d >> 8;
        int p = base[b] + atomicAdd(&h[b], 1);
        packbuf[p] = ((unsigned)src[e] << 8) | (unsigned)(d & 255);
    }
}

// ------- per-bucket CSR build: local hist, scan -> rowptr/dinv, scatter eidx -------
__global__ __launch_bounds__(512) void k_build(const unsigned* __restrict__ packbuf,
                                               const int* __restrict__ coff,
                                               int* __restrict__ rowptr,
                                               float* __restrict__ dinv,
                                               int* __restrict__ eidx, int N, int E) {
    __shared__ int cnt[256], loff[256], wsum[4];
    int b = blockIdx.x;
    int tx = threadIdx.x;  // 512
    int beg = coff[b], end = coff[b + 1];
    if (tx < 256) cnt[tx] = 0;
    __syncthreads();
    for (int e = beg + tx; e < end; e += 512)
        atomicAdd(&cnt[packbuf[e] & 255u], 1);
    __syncthreads();
    if (tx < 256) {
        int c = cnt[tx];
        int lane = tx & 63, wid = tx >> 6;
        int v = c;
#pragma unroll
        for (int off = 1; off < 64; off <<= 1) {
            int u = __shfl_up(v, off);
            if (lane >= off) v += u;
        }
        if (lane == 63) wsum[wid] = v;
        __syncthreads();
        int wbase = 0;
        for (int w = 0; w < wid; w++) wbase += wsum[w];
        int excl = wbase + v - c;
        loff[tx] = excl;
        int node = b * 256 + tx;
        if (node < N) {
            rowptr[node] = beg + excl;
            dinv[node] = rsqrtf(1.0f + (float)c);
        }
    } else {
        __syncthreads();
    }
    if (b == 0 && tx == 0) rowptr[N] = E;
    __syncthreads();
    for (int e = beg + tx; e < end; e += 512) {
        unsigned pk = packbuf[e];
        int pos = atomicAdd(&loff[pk & 255u], 1);
        eidx[beg + pos] = (int)(pk >> 8);
    }
}

// ---------------- column stats of x [N x 128] ----------------
__global__ void k_colstats_x(const float* __restrict__ x, float* __restrict__ xsum,
                             float* __restrict__ xsq, int N) {
    __shared__ float ls[256], lq[256];
    int tx = threadIdx.x;
    int col = tx & 127, half = tx >> 7;
    float s = 0.f, q = 0.f;
    for (int r = blockIdx.x * 2 + half; r < N; r += gridDim.x * 2) {
        float v = x[(long long)r * 128 + col];
        s += v; q += v * v;
    }
    ls[tx] = s; lq[tx] = q;
    __syncthreads();
    if (half == 0) {
        s = ls[tx] + ls[tx + 128];
        q = lq[tx] + lq[tx + 128];
        atomicAdd(&xsum[col], s);
        atomicAdd(&xsq[col], q);
    }
}

// ---------------- fold BN_in into Wp -> Wfold, bfold ----------------
__global__ void k_fold(const float* __restrict__ stats, const float* __restrict__ g,
                       const float* __restrict__ b, const float* __restrict__ Wp,
                       const float* __restrict__ bp, float* __restrict__ Wfold,
                       float* __restrict__ bfold, float invN) {
    __shared__ float sc[128], sh[128];
    int tx = threadIdx.x;
    if (tx < 128) {
        float mu = stats[tx] * invN;
        float var = stats[128 + tx] * invN - mu * mu;
        float s = g[tx] * rsqrtf(var + EPS);
        sc[tx] = s;
        sh[tx] = b[tx] - mu * s;
    }
    __syncthreads();
    for (int i = tx; i < 128 * 64; i += 256) {
        int c = i >> 6;
        Wfold[i] = Wp[i] * sc[c];
    }
    if (tx < 64) {
        float acc = bp[tx];
        for (int c = 0; c < 128; c++) acc += sh[c] * Wp[c * 64 + tx];
        bfold[tx] = acc;
    }
}

// ---------------- gemm1: relu(x @ Wfold + bfold) -> H [N x 64] ----------------
__global__ __launch_bounds__(256) void k_gemm1(const float* __restrict__ x,
                                               const float* __restrict__ Wf,
                                               const float* __restrict__ bf,
                                               float* __restrict__ H, int N) {
    int r = blockIdx.x * blockDim.x + threadIdx.x;
    if (r >= N) return;
    float acc[64];
#pragma unroll
    for (int j = 0; j < 64; j++) acc[j] = 0.f;
    const float4* x4 = (const float4*)(x + (long long)r * 128);
    for (int c4 = 0; c4 < 32; c4++) {
        float4 xv = x4[c4];
#pragma unroll
        for (int q = 0; q < 4; q++) {
            float xs = (q == 0) ? xv.x : (q == 1) ? xv.y : (q == 2) ? xv.z : xv.w;
            const float* wrow = Wf + (c4 * 4 + q) * 64;
#pragma unroll
            for (int j = 0; j < 64; j++) acc[j] += xs * wrow[j];
        }
    }
    float4* out4 = (float4*)(H + (long long)r * 64);
#pragma unroll
    for (int i = 0; i < 16; i++) {
        float4 v;
        v.x = fmaxf(acc[4 * i + 0] + bf[4 * i + 0], 0.f);
        v.y = fmaxf(acc[4 * i + 1] + bf[4 * i + 1], 0.f);
        v.z = fmaxf(acc[4 * i + 2] + bf[4 * i + 2], 0.f);
        v.w = fmaxf(acc[4 * i + 3] + bf[4 * i + 3], 0.f);
        out4[i] = v;
    }
}

// ------- gemm_scale: hs = (optional BN+relu(In)) @ W * dinv[row] -> Bpk (bf16) -------
// BNRELU variant computes BN scale/shift inline from raw stats (per block).
template <bool BNRELU>
__global__ __launch_bounds__(256) void k_gemm_scale(
    const float* __restrict__ In, const float* __restrict__ W,
    const float* __restrict__ dinv, const float* __restrict__ ssum,
    const float* __restrict__ ssq, const float* __restrict__ g,
    const float* __restrict__ bb, float invN, unsigned* __restrict__ Bpk, int N) {
    __shared__ float scs[64], shs[64];
    int tx = threadIdx.x;
    if (BNRELU) {
        if (tx < 64) {
            float mu = ssum[tx] * invN;
            float var = ssq[tx] * invN - mu * mu;
            float s = g[tx] * rsqrtf(var + EPS);
            scs[tx] = s;
            shs[tx] = bb[tx] - mu * s;
        }
        __syncthreads();
    }
    int r = blockIdx.x * blockDim.x + tx;
    if (r >= N) return;
    float acc[64];
#pragma unroll
    for (int j = 0; j < 64; j++) acc[j] = 0.f;
    const float4* in4 = (const float4*)(In + (long long)r * 64);
    for (int c4 = 0; c4 < 16; c4++) {
        float4 xv = in4[c4];
        if (BNRELU) {
            int cb = c4 * 4;
            xv.x = fmaxf(xv.x * scs[cb + 0] + shs[cb + 0], 0.f);
            xv.y = fmaxf(xv.y * scs[cb + 1] + shs[cb + 1], 0.f);
            xv.z = fmaxf(xv.z * scs[cb + 2] + shs[cb + 2], 0.f);
            xv.w = fmaxf(xv.w * scs[cb + 3] + shs[cb + 3], 0.f);
        }
#pragma unroll
        for (int q = 0; q < 4; q++) {
            float xs = (q == 0) ? xv.x : (q == 1) ? xv.y : (q == 2) ? xv.z : xv.w;
            const float* wrow = W + (c4 * 4 + q) * 64;
#pragma unroll
            for (int j = 0; j < 64; j++) acc[j] += xs * wrow[j];
        }
    }
    float dv = dinv[r];
    uint4* b4 = (uint4*)(Bpk + (long long)r * 32);
#pragma unroll
    for (int i = 0; i < 8; i++) {
        uint4 v;
        v.x = pack2(acc[8 * i + 0] * dv, acc[8 * i + 1] * dv);
        v.y = pack2(acc[8 * i + 2] * dv, acc[8 * i + 3] * dv);
        v.z = pack2(acc[8 * i + 4] * dv, acc[8 * i + 5] * dv);
        v.w = pack2(acc[8 * i + 6] * dv, acc[8 * i + 7] * dv);
        b4[i] = v;
    }
}

// ------- gather+finish: out[d] = dinv[d]*(hs[d] + sum_nbr hs[s]) + b; stats -------
// 8 lanes per node (uint4 = 8 bf16 feats each), 32 nodes per 256-block.
// Unroll-8 neighbor loop for MLP; shuffle-based stats reduction (no big LDS).
__global__ __launch_bounds__(256) void k_gather_finish(
    const uint4* __restrict__ B, const int* __restrict__ rowptr,
    const int* __restrict__ eidx, const float* __restrict__ dinv,
    const float* __restrict__ bias, float* __restrict__ Out,
    float* __restrict__ ssum, float* __restrict__ ssq, int N) {
    int tx = threadIdx.x;
    int g = tx >> 3;   // node slot in block (32 per block)
    int l = tx & 7;    // feature octet
    int d = blockIdx.x * 32 + g;

    float s[8], q[8];
#pragma unroll
    for (int j = 0; j < 8; j++) { s[j] = 0.f; q[j] = 0.f; }

    if (d < N) {
        int beg = rowptr[d], end = rowptr[d + 1];
        float acc[8];
        uint4 v0 = B[(long long)d * 8 + l];
        acc[0] = bf_lo(v0.x); acc[1] = bf_hi(v0.x);
        acc[2] = bf_lo(v0.y); acc[3] = bf_hi(v0.y);
        acc[4] = bf_lo(v0.z); acc[5] = bf_hi(v0.z);
        acc[6] = bf_lo(v0.w); acc[7] = bf_hi(v0.w);
        int k = beg;
        for (; k + 7 < end; k += 8) {
            int i0 = eidx[k + 0], i1 = eidx[k + 1], i2 = eidx[k + 2], i3 = eidx[k + 3];
            int i4 = eidx[k + 4], i5 = eidx[k + 5], i6 = eidx[k + 6], i7 = eidx[k + 7];
            uint4 a0 = B[(long long)i0 * 8 + l];
            uint4 a1 = B[(long long)i1 * 8 + l];
            uint4 a2 = B[(long long)i2 * 8 + l];
            uint4 a3 = B[(long long)i3 * 8 + l];
            uint4 a4 = B[(long long)i4 * 8 + l];
            uint4 a5 = B[(long long)i5 * 8 + l];
            uint4 a6 = B[(long long)i6 * 8 + l];
            uint4 a7 = B[(long long)i7 * 8 + l];
            acc_row(acc, a0); acc_row(acc, a1); acc_row(acc, a2); acc_row(acc, a3);
            acc_row(acc, a4); acc_row(acc, a5); acc_row(acc, a6); acc_row(acc, a7);
        }
        for (; k + 3 < end; k += 4) {
            int i0 = eidx[k + 0], i1 = eidx[k + 1], i2 = eidx[k + 2], i3 = eidx[k + 3];
            uint4 a0 = B[(long long)i0 * 8 + l];
            uint4 a1 = B[(long long)i1 * 8 + l];
            uint4 a2 = B[(long long)i2 * 8 + l];
            uint4 a3 = B[(long long)i3 * 8 + l];
            acc_row(acc, a0); acc_row(acc, a1); acc_row(acc, a2); acc_row(acc, a3);
        }
        for (; k + 1 < end; k += 2) {
            int i0 = eidx[k + 0], i1 = eidx[k + 1];
            uint4 a0 = B[(long long)i0 * 8 + l];
            uint4 a1 = B[(long long)i1 * 8 + l];
            acc_row(acc, a0); acc_row(acc, a1);
        }
        if (k < end) {
            uint4 a0 = B[(long long)eidx[k] * 8 + l];
            acc_row(acc, a0);
        }
        float dv = dinv[d];
        float4 o0, o1;
#pragma unroll
        for (int j = 0; j < 8; j++) {
            float v = acc[j] * dv + bias[8 * l + j];
            ((j < 4) ? (&o0.x)[j] : (&o1.x)[j - 4]) = v;
            s[j] += v; q[j] += v * v;
        }
        float4* outp = (float4*)(Out + (long long)d * 64 + 8 * l);
        outp[0] = o0;
        outp[1] = o1;
    }

    // reduce over the 8 node-groups within each wave via shuffles
#pragma unroll
    for (int m = 8; m <= 32; m <<= 1) {
#pragma unroll
        for (int j = 0; j < 8; j++) {
            s[j] += __shfl_xor(s[j], m, 64);
            q[j] += __shfl_xor(q[j], m, 64);
        }
    }
    __shared__ float ws_s[4][64], ws_q[4][64];
    int wv = tx >> 6, ln = tx & 63;
    if (ln < 8) {
#pragma unroll
        for (int j = 0; j < 8; j++) {
            ws_s[wv][ln * 8 + j] = s[j];
            ws_q[wv][ln * 8 + j] = q[j];
        }
    }
    __syncthreads();
    if (tx < 64) {
        float S = ws_s[0][tx] + ws_s[1][tx] + ws_s[2][tx] + ws_s[3][tx];
        float Q = ws_q[0][tx] + ws_q[1][tx] + ws_q[2][tx] + ws_q[3][tx];
        atomicAdd(&ssum[tx], S);
        atomicAdd(&ssq[tx], Q);
    }
}

// ---------------- final elementwise BN apply (stats inline, in-place safe) ----------------
__global__ __launch_bounds__(256) void k_final(const float* __restrict__ In,
                                               const float* __restrict__ ssum,
                                               const float* __restrict__ ssq,
                                               const float* __restrict__ g,
                                               const float* __restrict__ bb, float invN,
                                               float* __restrict__ out, int total4) {
    __shared__ float scs[64], shs[64];
    int tx = threadIdx.x;
    if (tx < 64) {
        float mu = ssum[tx] * invN;
        float var = ssq[tx] * invN - mu * mu;
        float s = g[tx] * rsqrtf(var + EPS);
        scs[tx] = s;
        shs[tx] = bb[tx] - mu * s;
    }
    __syncthreads();
    int t = blockIdx.x * blockDim.x + tx;
    if (t < total4) {
        float4 v = ((const float4*)In)[t];
        int j = (t * 4) & 63;
        v.x = v.x * scs[j + 0] + shs[j + 0];
        v.y = v.y * scs[j + 1] + shs[j + 1];
        v.z = v.z * scs[j + 2] + shs[j + 2];
        v.w = v.w * scs[j + 3] + shs[j + 3];
        ((float4*)out)[t] = v;
    }
}

extern "C" void kernel_launch(void* const* d_in, const int* in_sizes, int n_in,
                              void* d_out, int out_size, void* d_ws, size_t ws_size,
                              hipStream_t stream) {
    const float* x       = (const float*)d_in[0];
    const int*   ei      = (const int*)d_in[1];
    const float* bn_in_g = (const float*)d_in[2];
    const float* bn_in_b = (const float*)d_in[3];
    const float* Wp      = (const float*)d_in[4];
    const float* bp      = (const float*)d_in[5];
    const float* W1      = (const float*)d_in[6];
    const float* b1      = (const float*)d_in[7];
    const float* bn1_g   = (const float*)d_in[8];
    const float* bn1_b   = (const float*)d_in[9];
    const float* W2      = (const float*)d_in[10];
    const float* b2      = (const float*)d_in[11];
    const float* bn2_g   = (const float*)d_in[12];
    const float* bn2_b   = (const float*)d_in[13];

    int N = in_sizes[0] / 128;
    int E = in_sizes[1] / 2;
    const int* src = ei;
    const int* dst = ei + E;
    int NB = (N + 255) >> 8;  // coarse buckets (<=512)

    long long Npad = ((long long)N + 128) & ~127LL;
    int*   cc     = (int*)d_ws;           // 512
    int*   coff   = cc + 512;             // 513
    int*   cur    = coff + 640;           // 512
    int*   rowptr = cur + 512;            // Npad
    float* dinv   = (float*)(rowptr + Npad);
    float* stats  = dinv + Npad;          // 512
    float* Wfold  = stats + 512;          // 8192
    float* bfold  = Wfold + 8192;         // 64
    unsigned* packbuf = (unsigned*)(bfold + 64);          // E
    int*   eidx   = (int*)(packbuf + ((E + 127) & ~127)); // E
    unsigned* Bpk = (unsigned*)(eidx + ((E + 127) & ~127)); // N*32
    float* H      = (float*)d_out;        // N*64 intermediate + final out

    int nb = (N + 255) / 256;
    int gb = (N + 31) / 32;
    float invN = 1.0f / (float)N;

    // CSR build via two-level radix partition
    k_zero<<<1, 512, 0, stream>>>(cc, stats, NB);
    k_chist<<<512, 256, 0, stream>>>(dst, cc, E, NB);
    k_cscan<<<1, 512, 0, stream>>>(cc, coff, cur, NB, E);
    k_partition<<<(E + PCHUNK - 1) / PCHUNK, 256, 0, stream>>>(src, dst, cur, packbuf, E, NB);
    k_build<<<NB, 512, 0, stream>>>(packbuf, coff, rowptr, dinv, eidx, N, E);

    // input BN fold + projection
    k_colstats_x<<<1024, 256, 0, stream>>>(x, stats, stats + 128, N);
    k_fold<<<1, 256, 0, stream>>>(stats, bn_in_g, bn_in_b, Wp, bp, Wfold, bfold, invN);
    k_gemm1<<<nb, 256, 0, stream>>>(x, Wfold, bfold, H, N);

    // conv1
    k_gemm_scale<false><<<nb, 256, 0, stream>>>(H, W1, dinv, nullptr, nullptr, nullptr,
                                                nullptr, invN, Bpk, N);
    k_gather_finish<<<gb, 256, 0, stream>>>((const uint4*)Bpk, rowptr, eidx, dinv, b1, H,
                                            stats + 256, stats + 320, N);

    // conv2 (BN1 scale/shift computed inline from stats)
    k_gemm_scale<true><<<nb, 256, 0, stream>>>(H, W2, dinv, stats + 256, stats + 320,
                                               bn1_g, bn1_b, invN, Bpk, N);
    k_gather_finish<<<gb, 256, 0, stream>>>((const uint4*)Bpk, rowptr, eidx, dinv, b2, H,
                                            stats + 384, stats + 448, N);

    // final BN (scale/shift inline)
    k_final<<<(N * 16 + 255) / 256, 256, 0, stream>>>(H, stats + 384, stats + 448,
                                                      bn2_g, bn2_b, invN, H, N * 16);
}